// Round 7
// baseline (240.268 us; speedup 1.0000x reference)
//
#include <hip/hip_runtime.h>
#include <hip/hip_bf16.h>

typedef __bf16 bf16x8 __attribute__((ext_vector_type(8)));
typedef float  f32x4  __attribute__((ext_vector_type(4)));
typedef int    i32x4  __attribute__((ext_vector_type(4)));

#define K_N 524288
#define K_D 8
#define K_H 64
#define K_X 128

// ws layout:
//   [0, 81920)            packed bf16 B-fragments (16 W frags + 64 U frags, 64 lanes * 8 bf16 each)
//   [81920, 82432)        zero page (512 B of zeros; used as f32 by the x-GEMM path)
//   [131072, 131072+64MB) hb: h_prev converted to bf16, row-major [N][64]
#define WS_PACKED_SHORTS 40960
#define WS_ZERO_OFF_B    81920
#define WS_HB_OFF_B      131072
#define WS_NEEDED_BIG    (131072 + (size_t)K_N * K_H * 2)

// ---------------- prepass 1: pack W_in and U into MFMA B-fragment order (bf16) ----------------
// frag layout for v_mfma_f32_16x16x32_bf16 B operand: lane l holds B[k0 + 8*(l>>4) + j][ct*16 + (l&15)]
__global__ __launch_bounds__(64) void treernn_prepack(
    const float* __restrict__ W_in,
    const float* __restrict__ U,
    short* __restrict__ wsPacked,
    float* __restrict__ zerop)
{
    const int f = blockIdx.x;
    const int lane = threadIdx.x;
    if (f == 80) {                    // zero page: 512 B
        zerop[lane] = 0.0f;
        zerop[lane + 64] = 0.0f;
        return;
    }
    const int g = lane >> 4;
    const int c = lane & 15;
    bf16x8 v;
    if (f < 16) {                     // W_in: ks in 0..3 (K=128), ct in 0..3
        const int ks = f >> 2, ct = f & 3;
        #pragma unroll
        for (int j = 0; j < 8; ++j) {
            const int k = ks * 32 + 8 * g + j;
            v[j] = (__bf16)W_in[k * K_H + ct * 16 + c];
        }
    } else {                          // U: p in 0..7, ks in 0..1 (K=64), ct in 0..3
        const int f2 = f - 16;
        const int p = f2 >> 3, ks = (f2 >> 2) & 1, ct = f2 & 3;
        #pragma unroll
        for (int j = 0; j < 8; ++j) {
            const int k = ks * 32 + 8 * g + j;
            v[j] = (__bf16)U[p * K_H * K_H + k * K_H + ct * 16 + c];
        }
    }
    *reinterpret_cast<bf16x8*>(wsPacked + ((size_t)f * 64 + lane) * 8) = v;
}

// ---------------- prepass 2: h_prev (f32) -> hb (bf16), row-major [N][64] ----------------
__global__ __launch_bounds__(512) void treernn_h2bf16(
    const float* __restrict__ h_prev,
    __bf16* __restrict__ hb)
{
    const size_t tid = (size_t)blockIdx.x * 512 + threadIdx.x;   // 4,194,304 threads, 8 elems each
    const f32x4* s = reinterpret_cast<const f32x4*>(h_prev) + 2 * tid;
    const f32x4 v0 = s[0], v1 = s[1];
    bf16x8 o;
    #pragma unroll
    for (int j = 0; j < 4; ++j) {
        o[j]     = (__bf16)v0[j];
        o[j + 4] = (__bf16)v1[j];
    }
    reinterpret_cast<bf16x8*>(hb)[tid] = o;
}

// ---------------- main kernel (bf16 gathers): 512 thr = 8 waves, wave owns 32 nodes x 64 cols ----------------
// LDS 80 KiB -> 2 blocks/CU; VGPR<=128 -> 16 waves/CU. Gather pipeline depth-2 (consume p, p+1 in flight).
// Gathers are exec-mask PREDICATED: masked (node,p) pairs issue NO memory requests (lanes inactive),
// registers are zeroed instead. Discriminates request-side vs L3-line-side gather wall (r7 experiment).
__global__ __launch_bounds__(512, 4) void treernn_main_bf16(
    const float* __restrict__ x_embs,
    const float* __restrict__ x_mask,
    const __bf16* __restrict__ hb,
    const float* __restrict__ child_mask,
    const float* __restrict__ b_in,
    const float* __restrict__ b_aggr,
    const int*   __restrict__ child_idx,
    const short* __restrict__ wsPacked,
    const float* __restrict__ zerop,
    float* __restrict__ out)
{
    __shared__ __align__(16) short lds[WS_PACKED_SHORTS];   // 80 KiB

    {
        const i32x4* src = reinterpret_cast<const i32x4*>(wsPacked);
        i32x4* dst = reinterpret_cast<i32x4*>(lds);
        #pragma unroll
        for (int i = 0; i < 10; ++i)
            dst[threadIdx.x + i * 512] = src[threadIdx.x + i * 512];
    }

    const int lane = threadIdx.x & 63;
    const int wave = threadIdx.x >> 6;
    const int g = lane >> 4;          // k-group
    const int c = lane & 15;          // A row within row-tile / B col within col-tile
    const int base = (blockIdx.x * 8 + wave) * 32;

    // ---- child indices/masks ----
    int   idxs[2][8];
    float cms[2][8];
    #pragma unroll
    for (int rt = 0; rt < 2; ++rt) {
        const int node = base + rt * 16 + c;
        const i32x4* ip = reinterpret_cast<const i32x4*>(child_idx + (size_t)node * K_D);
        const i32x4 i0 = ip[0], i1 = ip[1];
        idxs[rt][0] = i0[0]; idxs[rt][1] = i0[1]; idxs[rt][2] = i0[2]; idxs[rt][3] = i0[3];
        idxs[rt][4] = i1[0]; idxs[rt][5] = i1[1]; idxs[rt][6] = i1[2]; idxs[rt][7] = i1[3];
        const f32x4* mp = reinterpret_cast<const f32x4*>(child_mask + (size_t)node * K_D);
        const f32x4 m0 = mp[0], m1 = mp[1];
        cms[rt][0] = m0[0]; cms[rt][1] = m0[1]; cms[rt][2] = m0[2]; cms[rt][3] = m0[3];
        cms[rt][4] = m1[0]; cms[rt][5] = m1[1]; cms[rt][6] = m1[2]; cms[rt][7] = m1[3];
    }

    f32x4 xmv[2];
    float xmrow[2];
    #pragma unroll
    for (int rt = 0; rt < 2; ++rt) {
        xmv[rt] = *reinterpret_cast<const f32x4*>(x_mask + base + rt * 16 + 4 * g);
        xmrow[rt] = x_mask[base + rt * 16 + c];
    }

    // gather buffers: [slot][rt][half]; each bf16x8 IS an A-fragment (no conversion needed)
    bf16x8 buf[2][2][2];
    const bf16x8 zfrag = {};

    // prologue A: issue predicated gathers for p=0 (fly under LDS staging barrier)
    #pragma unroll
    for (int rt = 0; rt < 2; ++rt) {
        bf16x8 v0 = zfrag, v1 = zfrag;
        if (cms[rt][0] != 0.0f) {
            const bf16x8* src = reinterpret_cast<const bf16x8*>(hb + (size_t)idxs[rt][0] * K_H);
            v0 = src[g];          // elems 8g..8g+7   (K first half)
            v1 = src[4 + g];      // elems 32+8g..    (K second half)
        }
        buf[0][rt][0] = v0;
        buf[0][rt][1] = v1;
    }

    f32x4 acc[2][4];
    #pragma unroll
    for (int rt = 0; rt < 2; ++rt)
        #pragma unroll
        for (int ct = 0; ct < 4; ++ct) {
            f32x4 z = {0.0f, 0.0f, 0.0f, 0.0f};
            acc[rt][ct] = z;
        }

    __syncthreads();

    // prologue B: issue predicated gathers for p=1 (fly under the whole x-GEMM)
    #pragma unroll
    for (int rt = 0; rt < 2; ++rt) {
        bf16x8 v0 = zfrag, v1 = zfrag;
        if (cms[rt][1] != 0.0f) {
            const bf16x8* src = reinterpret_cast<const bf16x8*>(hb + (size_t)idxs[rt][1] * K_H);
            v0 = src[g];
            v1 = src[4 + g];
        }
        buf[1][rt][0] = v0;
        buf[1][rt][1] = v1;
    }

    // ---------------- input GEMM: (x * xm) @ W_in (nontemporal x reads: keep L3 for hb) ----------------
    {
        #pragma unroll
        for (int rt = 0; rt < 2; ++rt) {
            const float* src = (xmrow[rt] != 0.0f) ? (x_embs + (size_t)(base + rt * 16 + c) * K_X) : zerop;
            #pragma unroll
            for (int ks = 0; ks < 4; ++ks) {
                const f32x4 a0 = __builtin_nontemporal_load(reinterpret_cast<const f32x4*>(src + ks * 32 + 8 * g));
                const f32x4 a1 = __builtin_nontemporal_load(reinterpret_cast<const f32x4*>(src + ks * 32 + 8 * g + 4));
                bf16x8 af;
                #pragma unroll
                for (int j = 0; j < 4; ++j) {
                    af[j]     = (__bf16)a0[j];
                    af[j + 4] = (__bf16)a1[j];
                }
                #pragma unroll
                for (int ct = 0; ct < 4; ++ct) {
                    const bf16x8 wf = *reinterpret_cast<const bf16x8*>(&lds[((ks * 4 + ct) * 64 + lane) * 8]);
                    acc[rt][ct] = __builtin_amdgcn_mfma_f32_16x16x32_bf16(af, wf, acc[rt][ct], 0, 0, 0);
                }
            }
        }
    }

    // ---------------- aggregation: sum_p gather(hb) @ U_p, depth-2 pipelined ----------------
    #pragma unroll
    for (int p = 0; p < 8; ++p) {
        const int pb = p & 1;

        // consume slot pb (issued at p-2); counted vmcnt keeps p+1 in flight
        const bf16x8 a0_0 = buf[pb][0][0], a1_0 = buf[pb][0][1];
        const bf16x8 a0_1 = buf[pb][1][0], a1_1 = buf[pb][1][1];

        // reissue slot pb with predicated gathers for p+2
        if (p < 6) {
            const int q = p + 2;
            #pragma unroll
            for (int rt = 0; rt < 2; ++rt) {
                bf16x8 v0 = zfrag, v1 = zfrag;
                if (cms[rt][q] != 0.0f) {
                    const bf16x8* src = reinterpret_cast<const bf16x8*>(hb + (size_t)idxs[rt][q] * K_H);
                    v0 = src[g];
                    v1 = src[4 + g];
                }
                buf[pb][rt][0] = v0;
                buf[pb][rt][1] = v1;
            }
        }

        // U fragments from LDS (lgkmcnt domain — decoupled from gather vmcnt)
        bf16x8 uf[2][4];
        #pragma unroll
        for (int ks = 0; ks < 2; ++ks)
            #pragma unroll
            for (int ct = 0; ct < 4; ++ct)
                uf[ks][ct] = *reinterpret_cast<const bf16x8*>(&lds[8192 + ((p * 8 + ks * 4 + ct) * 64 + lane) * 8]);

        #pragma unroll
        for (int ct = 0; ct < 4; ++ct)
            acc[0][ct] = __builtin_amdgcn_mfma_f32_16x16x32_bf16(a0_0, uf[0][ct], acc[0][ct], 0, 0, 0);
        #pragma unroll
        for (int ct = 0; ct < 4; ++ct)
            acc[0][ct] = __builtin_amdgcn_mfma_f32_16x16x32_bf16(a1_0, uf[1][ct], acc[0][ct], 0, 0, 0);
        #pragma unroll
        for (int ct = 0; ct < 4; ++ct)
            acc[1][ct] = __builtin_amdgcn_mfma_f32_16x16x32_bf16(a0_1, uf[0][ct], acc[1][ct], 0, 0, 0);
        #pragma unroll
        for (int ct = 0; ct < 4; ++ct)
            acc[1][ct] = __builtin_amdgcn_mfma_f32_16x16x32_bf16(a1_1, uf[1][ct], acc[1][ct], 0, 0, 0);
    }

    // ---------------- epilogue: + xm*b_in + b_aggr, tanh, nontemporal store ----------------
    #pragma unroll
    for (int ct = 0; ct < 4; ++ct) {
        const int col = ct * 16 + c;
        const float bi = b_in[col];
        const float ba = b_aggr[col];
        #pragma unroll
        for (int rt = 0; rt < 2; ++rt) {
            #pragma unroll
            for (int j = 0; j < 4; ++j) {
                const int node = base + rt * 16 + 4 * g + j;   // C/D row = 4*(lane>>4)+reg
                const float xm = xmv[rt][j];
                float h = acc[rt][ct][j] + ba + ((xm != 0.0f) ? bi : 0.0f);
                h = fminf(fmaxf(h, -9.0f), 9.0f);
                const float ex = __expf(2.0f * h);
                __builtin_nontemporal_store((ex - 1.0f) / (ex + 1.0f), &out[(size_t)node * K_H + col]);
            }
        }
    }
}

// ---------------- exact-f32 naive fallback (only if ws is too small) ----------------
__global__ void treernn_naive(
    const float* __restrict__ x_embs, const float* __restrict__ x_mask,
    const float* __restrict__ h_prev, const float* __restrict__ child_mask,
    const float* __restrict__ W_in,   const float* __restrict__ b_in,
    const float* __restrict__ U,      const float* __restrict__ b_aggr,
    const int*   __restrict__ child_idx, float* __restrict__ out)
{
    const int n = blockIdx.x * 4 + (threadIdx.x >> 6);
    const int e = threadIdx.x & 63;
    if (n >= K_N) return;
    float s = 0.0f;
    const float xm = x_mask[n];
    if (xm != 0.0f) {
        for (int k = 0; k < K_X; ++k) s += x_embs[(size_t)n * K_X + k] * W_in[k * K_H + e];
        s += b_in[e];
    }
    float a = b_aggr[e];
    for (int p = 0; p < K_D; ++p) {
        const float cm = child_mask[n * K_D + p];
        if (cm != 0.0f) {
            const int id = child_idx[n * K_D + p];
            const float* hp = h_prev + (size_t)id * K_H;
            for (int d = 0; d < K_H; ++d) a += hp[d] * U[p * K_H * K_H + d * K_H + e];
        }
    }
    float h = s + a;
    h = fminf(fmaxf(h, -9.0f), 9.0f);
    const float ex = __expf(2.0f * h);
    out[(size_t)n * K_H + e] = (ex - 1.0f) / (ex + 1.0f);
}

extern "C" void kernel_launch(void* const* d_in, const int* in_sizes, int n_in,
                              void* d_out, int out_size, void* d_ws, size_t ws_size,
                              hipStream_t stream) {
    const float* x_embs     = (const float*)d_in[0];
    const float* x_mask     = (const float*)d_in[1];
    const float* h_prev     = (const float*)d_in[2];
    const float* child_mask = (const float*)d_in[3];
    const float* W_in       = (const float*)d_in[4];
    const float* b_in       = (const float*)d_in[5];
    const float* U          = (const float*)d_in[6];
    const float* b_aggr     = (const float*)d_in[7];
    const int*   child_idx  = (const int*)d_in[8];
    float* out = (float*)d_out;

    if (d_ws != nullptr && ws_size >= WS_NEEDED_BIG) {
        short*  wsPacked = (short*)d_ws;
        float*  zerop    = (float*)((char*)d_ws + WS_ZERO_OFF_B);
        __bf16* hb       = (__bf16*)((char*)d_ws + WS_HB_OFF_B);
        treernn_prepack<<<81, 64, 0, stream>>>(W_in, U, wsPacked, zerop);
        treernn_h2bf16<<<K_N * K_H / 8 / 512, 512, 0, stream>>>(h_prev, hb);
        treernn_main_bf16<<<K_N / 256, 512, 0, stream>>>(x_embs, x_mask, hb, child_mask,
                                                         b_in, b_aggr, child_idx,
                                                         wsPacked, zerop, out);
    } else {
        treernn_naive<<<K_N / 4, 256, 0, stream>>>(x_embs, x_mask, h_prev, child_mask,
                                                   W_in, b_in, U, b_aggr, child_idx, out);
    }
}

// Round 8
// 154.184 us; speedup vs baseline: 1.5583x; 1.5583x over previous
//
#include <hip/hip_runtime.h>
#include <hip/hip_bf16.h>

typedef __bf16 bf16x8 __attribute__((ext_vector_type(8)));
typedef float  f32x4  __attribute__((ext_vector_type(4)));
typedef int    i32x4  __attribute__((ext_vector_type(4)));

#define K_N 524288
#define K_D 8
#define K_H 64
#define K_X 128

// ws layout:
//   [0, 81920)            packed bf16 B-fragments (16 W frags + 64 U frags, 64 lanes * 8 bf16 each)
//   [81920, 82432)        zero page (512 B of zeros; used as f32 and bf16)
//   [131072, 131072+64MB) hb: h_prev converted to bf16, row-major [N][64]
#define WS_PACKED_SHORTS 40960
#define WS_ZERO_OFF_B    81920
#define WS_HB_OFF_B      131072
#define WS_NEEDED_BIG    (131072 + (size_t)K_N * K_H * 2)

// ---------------- prepass 1: pack W_in and U into MFMA B-fragment order (bf16) ----------------
// frag layout for v_mfma_f32_16x16x32_bf16 B operand: lane l holds B[k0 + 8*(l>>4) + j][ct*16 + (l&15)]
__global__ __launch_bounds__(64) void treernn_prepack(
    const float* __restrict__ W_in,
    const float* __restrict__ U,
    short* __restrict__ wsPacked,
    float* __restrict__ zerop)
{
    const int f = blockIdx.x;
    const int lane = threadIdx.x;
    if (f == 80) {                    // zero page: 512 B
        zerop[lane] = 0.0f;
        zerop[lane + 64] = 0.0f;
        return;
    }
    const int g = lane >> 4;
    const int c = lane & 15;
    bf16x8 v;
    if (f < 16) {                     // W_in: ks in 0..3 (K=128), ct in 0..3
        const int ks = f >> 2, ct = f & 3;
        #pragma unroll
        for (int j = 0; j < 8; ++j) {
            const int k = ks * 32 + 8 * g + j;
            v[j] = (__bf16)W_in[k * K_H + ct * 16 + c];
        }
    } else {                          // U: p in 0..7, ks in 0..1 (K=64), ct in 0..3
        const int f2 = f - 16;
        const int p = f2 >> 3, ks = (f2 >> 2) & 1, ct = f2 & 3;
        #pragma unroll
        for (int j = 0; j < 8; ++j) {
            const int k = ks * 32 + 8 * g + j;
            v[j] = (__bf16)U[p * K_H * K_H + k * K_H + ct * 16 + c];
        }
    }
    *reinterpret_cast<bf16x8*>(wsPacked + ((size_t)f * 64 + lane) * 8) = v;
}

// ---------------- prepass 2: h_prev (f32) -> hb (bf16), row-major [N][64] ----------------
__global__ __launch_bounds__(512) void treernn_h2bf16(
    const float* __restrict__ h_prev,
    __bf16* __restrict__ hb)
{
    const size_t tid = (size_t)blockIdx.x * 512 + threadIdx.x;   // 4,194,304 threads, 8 elems each
    const f32x4* s = reinterpret_cast<const f32x4*>(h_prev) + 2 * tid;
    const f32x4 v0 = s[0], v1 = s[1];
    bf16x8 o;
    #pragma unroll
    for (int j = 0; j < 4; ++j) {
        o[j]     = (__bf16)v0[j];
        o[j + 4] = (__bf16)v1[j];
    }
    reinterpret_cast<bf16x8*>(hb)[tid] = o;
}

// ---------------- main kernel (bf16 gathers): 512 thr = 8 waves, wave owns 32 nodes x 64 cols ----------------
// LDS 80 KiB -> 2 blocks/CU; VGPR<=128 -> 16 waves/CU. Gather pipeline depth-2 (consume p, p+1 in flight).
// Gather phase runs at the L2-miss line-rate wall (~1 line/cy/XCD ~ 18.8G lines/s).
// DO NOT: add ring depth (r3/r5 neutral/neg), raise occupancy (r2 neutral), or predicate gathers with
// branches (r7: divergent CF pessimizes waitcnt insertion, destroys pipeline, 110 -> 255 us).
__global__ __launch_bounds__(512, 4) void treernn_main_bf16(
    const float* __restrict__ x_embs,
    const float* __restrict__ x_mask,
    const __bf16* __restrict__ hb,
    const float* __restrict__ child_mask,
    const float* __restrict__ b_in,
    const float* __restrict__ b_aggr,
    const int*   __restrict__ child_idx,
    const short* __restrict__ wsPacked,
    const float* __restrict__ zerop,
    float* __restrict__ out)
{
    __shared__ __align__(16) short lds[WS_PACKED_SHORTS];   // 80 KiB

    {
        const i32x4* src = reinterpret_cast<const i32x4*>(wsPacked);
        i32x4* dst = reinterpret_cast<i32x4*>(lds);
        #pragma unroll
        for (int i = 0; i < 10; ++i)
            dst[threadIdx.x + i * 512] = src[threadIdx.x + i * 512];
    }

    const int lane = threadIdx.x & 63;
    const int wave = threadIdx.x >> 6;
    const int g = lane >> 4;          // k-group
    const int c = lane & 15;          // A row within row-tile / B col within col-tile
    const int base = (blockIdx.x * 8 + wave) * 32;
    const bf16x8* zb = reinterpret_cast<const bf16x8*>(zerop);

    // ---- child indices/masks ----
    int   idxs[2][8];
    float cms[2][8];
    #pragma unroll
    for (int rt = 0; rt < 2; ++rt) {
        const int node = base + rt * 16 + c;
        const i32x4* ip = reinterpret_cast<const i32x4*>(child_idx + (size_t)node * K_D);
        const i32x4 i0 = ip[0], i1 = ip[1];
        idxs[rt][0] = i0[0]; idxs[rt][1] = i0[1]; idxs[rt][2] = i0[2]; idxs[rt][3] = i0[3];
        idxs[rt][4] = i1[0]; idxs[rt][5] = i1[1]; idxs[rt][6] = i1[2]; idxs[rt][7] = i1[3];
        const f32x4* mp = reinterpret_cast<const f32x4*>(child_mask + (size_t)node * K_D);
        const f32x4 m0 = mp[0], m1 = mp[1];
        cms[rt][0] = m0[0]; cms[rt][1] = m0[1]; cms[rt][2] = m0[2]; cms[rt][3] = m0[3];
        cms[rt][4] = m1[0]; cms[rt][5] = m1[1]; cms[rt][6] = m1[2]; cms[rt][7] = m1[3];
    }

    f32x4 xmv[2];
    float xmrow[2];
    #pragma unroll
    for (int rt = 0; rt < 2; ++rt) {
        xmv[rt] = *reinterpret_cast<const f32x4*>(x_mask + base + rt * 16 + 4 * g);
        xmrow[rt] = x_mask[base + rt * 16 + c];
    }

    // gather buffers: [slot][rt][half]; each bf16x8 IS an A-fragment (no conversion needed)
    bf16x8 buf[2][2][2];

    // prologue A: issue gathers for p=0 (fly under LDS staging barrier)
    #pragma unroll
    for (int rt = 0; rt < 2; ++rt) {
        const bf16x8* src = (cms[rt][0] != 0.0f)
            ? reinterpret_cast<const bf16x8*>(hb + (size_t)idxs[rt][0] * K_H) : zb;
        buf[0][rt][0] = src[g];          // elems 8g..8g+7   (K first half)
        buf[0][rt][1] = src[4 + g];      // elems 32+8g..    (K second half)
    }

    f32x4 acc[2][4];
    #pragma unroll
    for (int rt = 0; rt < 2; ++rt)
        #pragma unroll
        for (int ct = 0; ct < 4; ++ct) {
            f32x4 z = {0.0f, 0.0f, 0.0f, 0.0f};
            acc[rt][ct] = z;
        }

    __syncthreads();

    // prologue B: issue gathers for p=1 (fly under the whole x-GEMM)
    #pragma unroll
    for (int rt = 0; rt < 2; ++rt) {
        const bf16x8* src = (cms[rt][1] != 0.0f)
            ? reinterpret_cast<const bf16x8*>(hb + (size_t)idxs[rt][1] * K_H) : zb;
        buf[1][rt][0] = src[g];
        buf[1][rt][1] = src[4 + g];
    }

    // ---------------- input GEMM: (x * xm) @ W_in (nontemporal x reads: keep L3 for hb) ----------------
    {
        #pragma unroll
        for (int rt = 0; rt < 2; ++rt) {
            const float* src = (xmrow[rt] != 0.0f) ? (x_embs + (size_t)(base + rt * 16 + c) * K_X) : zerop;
            #pragma unroll
            for (int ks = 0; ks < 4; ++ks) {
                const f32x4 a0 = __builtin_nontemporal_load(reinterpret_cast<const f32x4*>(src + ks * 32 + 8 * g));
                const f32x4 a1 = __builtin_nontemporal_load(reinterpret_cast<const f32x4*>(src + ks * 32 + 8 * g + 4));
                bf16x8 af;
                #pragma unroll
                for (int j = 0; j < 4; ++j) {
                    af[j]     = (__bf16)a0[j];
                    af[j + 4] = (__bf16)a1[j];
                }
                #pragma unroll
                for (int ct = 0; ct < 4; ++ct) {
                    const bf16x8 wf = *reinterpret_cast<const bf16x8*>(&lds[((ks * 4 + ct) * 64 + lane) * 8]);
                    acc[rt][ct] = __builtin_amdgcn_mfma_f32_16x16x32_bf16(af, wf, acc[rt][ct], 0, 0, 0);
                }
            }
        }
    }

    // ---------------- aggregation: sum_p gather(hb) @ U_p, depth-2 pipelined ----------------
    #pragma unroll
    for (int p = 0; p < 8; ++p) {
        const int pb = p & 1;

        // consume slot pb (issued at p-2); counted vmcnt keeps p+1 in flight
        const bf16x8 a0_0 = buf[pb][0][0], a1_0 = buf[pb][0][1];
        const bf16x8 a0_1 = buf[pb][1][0], a1_1 = buf[pb][1][1];

        // reissue slot pb with gathers for p+2
        if (p < 6) {
            const int q = p + 2;
            #pragma unroll
            for (int rt = 0; rt < 2; ++rt) {
                const bf16x8* src = (cms[rt][q] != 0.0f)
                    ? reinterpret_cast<const bf16x8*>(hb + (size_t)idxs[rt][q] * K_H) : zb;
                buf[pb][rt][0] = src[g];
                buf[pb][rt][1] = src[4 + g];
            }
        }

        // U fragments from LDS (lgkmcnt domain — decoupled from gather vmcnt)
        bf16x8 uf[2][4];
        #pragma unroll
        for (int ks = 0; ks < 2; ++ks)
            #pragma unroll
            for (int ct = 0; ct < 4; ++ct)
                uf[ks][ct] = *reinterpret_cast<const bf16x8*>(&lds[8192 + ((p * 8 + ks * 4 + ct) * 64 + lane) * 8]);

        #pragma unroll
        for (int ct = 0; ct < 4; ++ct)
            acc[0][ct] = __builtin_amdgcn_mfma_f32_16x16x32_bf16(a0_0, uf[0][ct], acc[0][ct], 0, 0, 0);
        #pragma unroll
        for (int ct = 0; ct < 4; ++ct)
            acc[0][ct] = __builtin_amdgcn_mfma_f32_16x16x32_bf16(a1_0, uf[1][ct], acc[0][ct], 0, 0, 0);
        #pragma unroll
        for (int ct = 0; ct < 4; ++ct)
            acc[1][ct] = __builtin_amdgcn_mfma_f32_16x16x32_bf16(a0_1, uf[0][ct], acc[1][ct], 0, 0, 0);
        #pragma unroll
        for (int ct = 0; ct < 4; ++ct)
            acc[1][ct] = __builtin_amdgcn_mfma_f32_16x16x32_bf16(a1_1, uf[1][ct], acc[1][ct], 0, 0, 0);
    }

    // ---------------- epilogue: + xm*b_in + b_aggr, tanh, nontemporal store ----------------
    #pragma unroll
    for (int ct = 0; ct < 4; ++ct) {
        const int col = ct * 16 + c;
        const float bi = b_in[col];
        const float ba = b_aggr[col];
        #pragma unroll
        for (int rt = 0; rt < 2; ++rt) {
            #pragma unroll
            for (int j = 0; j < 4; ++j) {
                const int node = base + rt * 16 + 4 * g + j;   // C/D row = 4*(lane>>4)+reg
                const float xm = xmv[rt][j];
                float h = acc[rt][ct][j] + ba + ((xm != 0.0f) ? bi : 0.0f);
                h = fminf(fmaxf(h, -9.0f), 9.0f);
                const float ex = __expf(2.0f * h);
                __builtin_nontemporal_store((ex - 1.0f) / (ex + 1.0f), &out[(size_t)node * K_H + col]);
            }
        }
    }
}

// ---------------- exact-f32 naive fallback (only if ws is too small) ----------------
__global__ void treernn_naive(
    const float* __restrict__ x_embs, const float* __restrict__ x_mask,
    const float* __restrict__ h_prev, const float* __restrict__ child_mask,
    const float* __restrict__ W_in,   const float* __restrict__ b_in,
    const float* __restrict__ U,      const float* __restrict__ b_aggr,
    const int*   __restrict__ child_idx, float* __restrict__ out)
{
    const int n = blockIdx.x * 4 + (threadIdx.x >> 6);
    const int e = threadIdx.x & 63;
    if (n >= K_N) return;
    float s = 0.0f;
    const float xm = x_mask[n];
    if (xm != 0.0f) {
        for (int k = 0; k < K_X; ++k) s += x_embs[(size_t)n * K_X + k] * W_in[k * K_H + e];
        s += b_in[e];
    }
    float a = b_aggr[e];
    for (int p = 0; p < K_D; ++p) {
        const float cm = child_mask[n * K_D + p];
        if (cm != 0.0f) {
            const int id = child_idx[n * K_D + p];
            const float* hp = h_prev + (size_t)id * K_H;
            for (int d = 0; d < K_H; ++d) a += hp[d] * U[p * K_H * K_H + d * K_H + e];
        }
    }
    float h = s + a;
    h = fminf(fmaxf(h, -9.0f), 9.0f);
    const float ex = __expf(2.0f * h);
    out[(size_t)n * K_H + e] = (ex - 1.0f) / (ex + 1.0f);
}

extern "C" void kernel_launch(void* const* d_in, const int* in_sizes, int n_in,
                              void* d_out, int out_size, void* d_ws, size_t ws_size,
                              hipStream_t stream) {
    const float* x_embs     = (const float*)d_in[0];
    const float* x_mask     = (const float*)d_in[1];
    const float* h_prev     = (const float*)d_in[2];
    const float* child_mask = (const float*)d_in[3];
    const float* W_in       = (const float*)d_in[4];
    const float* b_in       = (const float*)d_in[5];
    const float* U          = (const float*)d_in[6];
    const float* b_aggr     = (const float*)d_in[7];
    const int*   child_idx  = (const int*)d_in[8];
    float* out = (float*)d_out;

    if (d_ws != nullptr && ws_size >= WS_NEEDED_BIG) {
        short*  wsPacked = (short*)d_ws;
        float*  zerop    = (float*)((char*)d_ws + WS_ZERO_OFF_B);
        __bf16* hb       = (__bf16*)((char*)d_ws + WS_HB_OFF_B);
        treernn_prepack<<<81, 64, 0, stream>>>(W_in, U, wsPacked, zerop);
        treernn_h2bf16<<<K_N * K_H / 8 / 512, 512, 0, stream>>>(h_prev, hb);
        treernn_main_bf16<<<K_N / 256, 512, 0, stream>>>(x_embs, x_mask, hb, child_mask,
                                                         b_in, b_aggr, child_idx,
                                                         wsPacked, zerop, out);
    } else {
        treernn_naive<<<K_N / 4, 256, 0, stream>>>(x_embs, x_mask, h_prev, child_mask,
                                                   W_in, b_in, U, b_aggr, child_idx, out);
    }
}